// Round 4
// baseline (169.360 us; speedup 1.0000x reference)
//
#include <hip/hip_runtime.h>

#define NB 32
#define NH 720
#define NW 1280
#define NHW (NH * NW)        // 921600
#define NV4 (NHW / 4)        // 230400 float4 per image
#define KTOP 1024
#define CAP 2048             // gather capacity per image (~830 expected)
#define BPI 60               // blocks per image
#define V4PB (NV4 / BPI)     // 3840 float4 per block
#define BATCH 5
#define OITER 3              // 15 float4 per thread = OITER * BATCH
#define LCAP 512             // per-block candidate capacity (expected ~14)

typedef float vf4 __attribute__((ext_vector_type(4)));   // native vector for nt-store

// ------- K1: zero the output map + gather candidates >= threshold -------
// Each block owns a contiguous 3840-float4 chunk fully inside one image.
// 5 loads kept in flight per wave (named registers); zero-fill uses
// non-temporal stores so the write stream doesn't evict prob from L3.
// Candidates stage in LDS; ONE global atomic per block reserves the slice.
__global__ __launch_bounds__(256)
void k_zero_gather(const float* __restrict__ prob,
                   const float* __restrict__ thr_p,
                   float* __restrict__ out,
                   int* __restrict__ counts,
                   float2* __restrict__ cand) {
  const int img = blockIdx.x / BPI;
  const int blk = blockIdx.x - img * BPI;
  const float thr = thr_p[0];

  __shared__ int lcount;
  __shared__ int lbase;
  __shared__ float2 lcand[LCAP];
  if (threadIdx.x == 0) lcount = 0;
  __syncthreads();

  const float4* __restrict__ in4 =
      reinterpret_cast<const float4*>(prob) + (size_t)img * NV4 + blk * V4PB + threadIdx.x;
  vf4* __restrict__ out4 =
      reinterpret_cast<vf4*>(out) + (size_t)img * NV4 + blk * V4PB + threadIdx.x;
  const int idx0 = (blk * V4PB + threadIdx.x) * 4;   // flat idx within image
  const vf4 z = {0.f, 0.f, 0.f, 0.f};

#pragma unroll
  for (int it = 0; it < OITER; ++it) {
    const int o0 = (it * BATCH + 0) * 256;
    const int o1 = (it * BATCH + 1) * 256;
    const int o2 = (it * BATCH + 2) * 256;
    const int o3 = (it * BATCH + 3) * 256;
    const int o4 = (it * BATCH + 4) * 256;
    const float4 p0 = in4[o0];
    const float4 p1 = in4[o1];
    const float4 p2 = in4[o2];
    const float4 p3 = in4[o3];
    const float4 p4 = in4[o4];
    __builtin_nontemporal_store(z, &out4[o0]);
    __builtin_nontemporal_store(z, &out4[o1]);
    __builtin_nontemporal_store(z, &out4[o2]);
    __builtin_nontemporal_store(z, &out4[o3]);
    __builtin_nontemporal_store(z, &out4[o4]);
#define CHECKC(val, off, c)                                              \
    if ((val) >= thr) {                                                  \
      const int pos = atomicAdd(&lcount, 1);                             \
      if (pos < LCAP)                                                    \
        lcand[pos] = make_float2((val), __int_as_float(idx0 + (off) * 4 + (c))); \
    }
#define CHECK4(p, off) CHECKC((p).x, off, 0) CHECKC((p).y, off, 1) \
                       CHECKC((p).z, off, 2) CHECKC((p).w, off, 3)
    CHECK4(p0, o0) CHECK4(p1, o1) CHECK4(p2, o2) CHECK4(p3, o3) CHECK4(p4, o4)
#undef CHECK4
#undef CHECKC
  }
  __syncthreads();

  const int ln = min(lcount, LCAP);
  if (threadIdx.x == 0) lbase = atomicAdd(&counts[img], ln);
  __syncthreads();
  const int b = lbase;
  for (int i = threadIdx.x; i < ln; i += 256) {
    const int pos = b + i;
    if (pos < CAP) cand[(size_t)img * CAP + pos] = lcand[i];
  }
}

// plain zeroing (fallback path)
__global__ void k_zero_out(float* __restrict__ out) {
  const int total4 = NB * NV4;
  const int stride = gridDim.x * blockDim.x;
  const float4 z = make_float4(0.f, 0.f, 0.f, 0.f);
  for (int v = blockIdx.x * blockDim.x + threadIdx.x; v < total4; v += stride)
    reinterpret_cast<float4*>(out)[v] = z;
}

// ---- K2+K3 fused: rank (stable top_k order) + conflict flag + greedy NMS ----
// One 1024-thread block per image. Thread j computes, in one O(n) LDS pass:
//   rank = #{i : (s_i > s_j) or (s_i == s_j and idx_i < idx_j)}  (== top_k order)
//   conf = exists i != j with iou(i,j) > 0.1
// Sorted arrays live in LDS; conflicted subset is compacted via ballot and
// exact greedy NMS (restricted to the conflict graph == full greedy) runs on
// wave 0; kept scores scatter to the zeroed output map.
__global__ __launch_bounds__(1024)
void k_nms(const int* __restrict__ size_p,
           const int* __restrict__ counts,
           const float2* __restrict__ cand,
           float* __restrict__ out) {
  const int img = blockIdx.x;
  const int tid = threadIdx.x;
  const int n = min(counts[img], CAP);
  const int m = min(n, KTOP);
  const float S = (float)size_p[0];   // box side == 2*half (exact, even for odd size)
  const float A = 2.f * S * S;        // iou > 0.1  <=>  11*inter > A (exact small ints)

  __shared__ float4 cd[CAP];          // (score, y, x, idx-bits)
  __shared__ float ssc[KTOP];
  __shared__ int   sgi[KTOP];
  __shared__ int   keepf[KTOP];
  __shared__ int   flagA[KTOP];
  __shared__ int   lst[KTOP];
  __shared__ int   wtot[16], wbase[16];
  __shared__ int   nc_sh;

  for (int i = tid; i < n; i += 1024) {
    const float2 e2 = cand[(size_t)img * CAP + i];
    const int e = __float_as_int(e2.y);
    const int y = e / NW;
    cd[i] = make_float4(e2.x, (float)y, (float)(e - y * NW), e2.y);
  }
  keepf[tid] = 0;
  flagA[tid] = 0;
  __syncthreads();

  // rank + conflict pass (each rank r < m is written exactly once)
  for (int j = tid; j < n; j += 1024) {
    const float4 me = cd[j];
    const float sj = me.x, yj = me.y, xj = me.z;
    const int gj = __float_as_int(me.w);
    int r = 0;
    int conf = 0;
    for (int i = 0; i < n; ++i) {
      const float4 o = cd[i];                     // lockstep same-address broadcast
      const int g2 = __float_as_int(o.w);
      r += (o.x > sj) || (o.x == sj && g2 < gj);  // stable top_k tie order
      const float iy = S - fabsf(yj - o.y);
      const float ix = S - fabsf(xj - o.z);
      const float inter = (fminf(iy, ix) > 0.f) ? iy * ix : 0.f;
      conf |= (int)((i != j) & (11.f * inter > A));
    }
    if (r < KTOP) {
      ssc[r] = sj;
      sgi[r] = gj;
      keepf[r] = 1;
      flagA[r] = conf;
    }
  }
  __syncthreads();

  // ballot-based compaction of conflicted candidates (priority order preserved)
  const int wid = tid >> 6, lane = tid & 63;
  const int flagv = flagA[tid];
  const unsigned long long mask = __ballot(flagv != 0);
  if (lane == 0) wtot[wid] = __popcll(mask);
  __syncthreads();
  if (tid == 0) {
    int s = 0;
    for (int w = 0; w < 16; ++w) { wbase[w] = s; s += wtot[w]; }
    nc_sh = s;
  }
  __syncthreads();
  if (flagv)
    lst[wbase[wid] + __popcll(mask & ((1ull << lane) - 1ull))] = tid;
  const int nc = nc_sh;
  __syncthreads();

  // exact greedy NMS over the conflicted subset (wave 0 only). Isolated
  // candidates can neither suppress nor be suppressed => equals full greedy.
  if (tid < 64) {
    for (int a = 1; a < nc; ++a) {
      const int j = lst[a];
      const int g = sgi[j];
      const int yj0 = g / NW;
      const float yjf = (float)yj0, xjf = (float)(g - yj0 * NW);
      bool sup = false;
      for (int base = 0; base < a; base += 64) {
        const int b = base + tid;
        bool hit = false;
        if (b < a) {
          const int i2 = lst[b];
          if (keepf[i2]) {
            const int g2 = sgi[i2];
            const int yi0 = g2 / NW;
            const float iy = S - fabsf(yjf - (float)yi0);
            const float ix = S - fabsf(xjf - (float)(g2 - yi0 * NW));
            hit = (fminf(iy, ix) > 0.f) && (11.f * iy * ix > A);
          }
        }
        if (__any(hit)) { sup = true; break; }
      }
      if (tid == 0 && sup) keepf[j] = 0;
    }
  }
  __syncthreads();

  if (tid < m && keepf[tid])
    out[(size_t)img * NHW + sgi[tid]] = ssc[tid];
}

// --------- fallback: monolithic per-image kernel (no workspace) ---------
__global__ __launch_bounds__(1024)
void k_nms_mono(const float* __restrict__ prob,
                const float* __restrict__ thr_p,
                const int* __restrict__ size_p,
                float* __restrict__ out) {
  const int img = blockIdx.x;
  const int tid = threadIdx.x;
  const float thr = thr_p[0];
  const float S = (float)size_p[0];
  const float A = 2.f * S * S;
  const float* ip = prob + (size_t)img * NHW;

  __shared__ float sc[CAP];
  __shared__ int   gi[CAP];
  __shared__ float ssc[KTOP];
  __shared__ int   sgi[KTOP];
  __shared__ int   keepf[KTOP];
  __shared__ int   sh_n;

  if (tid == 0) sh_n = 0;
  __syncthreads();
  for (int e = tid; e < NHW; e += 1024) {
    const float p = ip[e];
    if (p >= thr) {
      const int pos = atomicAdd(&sh_n, 1);
      if (pos < CAP) { sc[pos] = p; gi[pos] = e; }
    }
  }
  __syncthreads();
  const int n = min(sh_n, CAP);
  const int m = min(n, KTOP);

  for (int j = tid; j < n; j += 1024) {
    const float sj = sc[j]; const int gj = gi[j];
    int r = 0;
    for (int i = 0; i < n; ++i)
      r += (sc[i] > sj) || (sc[i] == sj && gi[i] < gj);
    if (r < KTOP) { ssc[r] = sj; sgi[r] = gj; }
  }
  keepf[tid] = (tid < m);
  __syncthreads();

  for (int i = 0; i < m; ++i) {
    __syncthreads();
    if (!keepf[i]) continue;
    const int g = sgi[i];
    const int yi0 = g / NW;
    const float yi = (float)yi0, xi = (float)(g - yi0 * NW);
    if (tid > i && tid < m && keepf[tid]) {
      const int g2 = sgi[tid];
      const int yj0 = g2 / NW;
      const float iy = S - fabsf(yi - (float)yj0);
      const float ix = S - fabsf(xi - (float)(g2 - yj0 * NW));
      if (fminf(iy, ix) > 0.f && 11.f * iy * ix > A) keepf[tid] = 0;
    }
  }
  __syncthreads();
  if (tid < m && keepf[tid])
    out[(size_t)img * NHW + sgi[tid]] = ssc[tid];
}

extern "C" void kernel_launch(void* const* d_in, const int* in_sizes, int n_in,
                              void* d_out, int out_size, void* d_ws, size_t ws_size,
                              hipStream_t stream) {
  const float* prob   = (const float*)d_in[0];
  const int*   size_p = (const int*)d_in[1];
  const float* thr_p  = (const float*)d_in[2];
  float* out = (float*)d_out;

  const size_t counts_b = 128;                              // NB ints, padded
  const size_t cand_b   = (size_t)NB * CAP * sizeof(float2);
  const size_t needed   = counts_b + cand_b;                // ~512 KB

  if (ws_size >= needed) {
    int*    counts = (int*)d_ws;
    float2* cand   = (float2*)((char*)d_ws + counts_b);
    (void)hipMemsetAsync(counts, 0, NB * sizeof(int), stream);
    k_zero_gather<<<NB * BPI, 256, 0, stream>>>(prob, thr_p, out, counts, cand);
    k_nms<<<NB, KTOP, 0, stream>>>(size_p, counts, cand, out);
  } else {
    k_zero_out<<<2048, 256, 0, stream>>>(out);
    k_nms_mono<<<NB, 1024, 0, stream>>>(prob, thr_p, size_p, out);
  }
}

// Round 5
// 67.494 us; speedup vs baseline: 2.5093x; 2.5093x over previous
//
#include <hip/hip_runtime.h>

#define NB 32
#define NH 720
#define NW 1280
#define NHW (NH * NW)        // 921600
#define NV4 (NHW / 4)        // 230400 float4 per image
#define KTOP 1024
#define CAP 2048             // gather capacity per image (~830 expected)
#define BPI 60               // blocks per image
#define V4PB (NV4 / BPI)     // 3840 float4 per block
#define BATCH 5
#define OITER 3              // 15 float4 per thread = OITER * BATCH
#define LCAP 512             // per-block candidate capacity (expected ~14)

typedef float vf4 __attribute__((ext_vector_type(4)));   // native vector for nt-store

// ------- K1: zero the output map + gather candidates >= threshold -------
// (unchanged from R4 — measured at the 236 MB copy roofline, ~38 us)
__global__ __launch_bounds__(256)
void k_zero_gather(const float* __restrict__ prob,
                   const float* __restrict__ thr_p,
                   float* __restrict__ out,
                   int* __restrict__ counts,
                   float2* __restrict__ cand) {
  const int img = blockIdx.x / BPI;
  const int blk = blockIdx.x - img * BPI;
  const float thr = thr_p[0];

  __shared__ int lcount;
  __shared__ int lbase;
  __shared__ float2 lcand[LCAP];
  if (threadIdx.x == 0) lcount = 0;
  __syncthreads();

  const float4* __restrict__ in4 =
      reinterpret_cast<const float4*>(prob) + (size_t)img * NV4 + blk * V4PB + threadIdx.x;
  vf4* __restrict__ out4 =
      reinterpret_cast<vf4*>(out) + (size_t)img * NV4 + blk * V4PB + threadIdx.x;
  const int idx0 = (blk * V4PB + threadIdx.x) * 4;   // flat idx within image
  const vf4 z = {0.f, 0.f, 0.f, 0.f};

#pragma unroll
  for (int it = 0; it < OITER; ++it) {
    const int o0 = (it * BATCH + 0) * 256;
    const int o1 = (it * BATCH + 1) * 256;
    const int o2 = (it * BATCH + 2) * 256;
    const int o3 = (it * BATCH + 3) * 256;
    const int o4 = (it * BATCH + 4) * 256;
    const float4 p0 = in4[o0];
    const float4 p1 = in4[o1];
    const float4 p2 = in4[o2];
    const float4 p3 = in4[o3];
    const float4 p4 = in4[o4];
    __builtin_nontemporal_store(z, &out4[o0]);
    __builtin_nontemporal_store(z, &out4[o1]);
    __builtin_nontemporal_store(z, &out4[o2]);
    __builtin_nontemporal_store(z, &out4[o3]);
    __builtin_nontemporal_store(z, &out4[o4]);
#define CHECKC(val, off, c)                                              \
    if ((val) >= thr) {                                                  \
      const int pos = atomicAdd(&lcount, 1);                             \
      if (pos < LCAP)                                                    \
        lcand[pos] = make_float2((val), __int_as_float(idx0 + (off) * 4 + (c))); \
    }
#define CHECK4(p, off) CHECKC((p).x, off, 0) CHECKC((p).y, off, 1) \
                       CHECKC((p).z, off, 2) CHECKC((p).w, off, 3)
    CHECK4(p0, o0) CHECK4(p1, o1) CHECK4(p2, o2) CHECK4(p3, o3) CHECK4(p4, o4)
#undef CHECK4
#undef CHECKC
  }
  __syncthreads();

  const int ln = min(lcount, LCAP);
  if (threadIdx.x == 0) lbase = atomicAdd(&counts[img], ln);
  __syncthreads();
  const int b = lbase;
  for (int i = threadIdx.x; i < ln; i += 256) {
    const int pos = b + i;
    if (pos < CAP) cand[(size_t)img * CAP + pos] = lcand[i];
  }
}

// plain zeroing (fallback path)
__global__ void k_zero_out(float* __restrict__ out) {
  const int total4 = NB * NV4;
  const int stride = gridDim.x * blockDim.x;
  const float4 z = make_float4(0.f, 0.f, 0.f, 0.f);
  for (int v = blockIdx.x * blockDim.x + threadIdx.x; v < total4; v += stride)
    reinterpret_cast<float4*>(out)[v] = z;
}

// ---- K2: O(n * local) NMS via row-bucketed conflict detection ----
// One 1024-thread block per image. For n <= KTOP no ranking is needed (all
// thresholded candidates are in the top-K). Conflicts (iou > 0.1) require
// |dy|,|dx| <= S-1, so counting-sort by row + 7-row window scan finds the
// exact conflicted subset in O(n * ~6). That subset (~27) is sorted by
// (score desc, idx asc) = top_k order, greedy NMS runs on it (provably equal
// to full greedy), kept scores scatter to the zeroed map.
// If n > KTOP (never with this data): O(n^2) rank pass filters to exactly
// the top-KTOP set first, then the same pipeline runs.
__global__ __launch_bounds__(1024)
void k_nms(const int* __restrict__ size_p,
           const int* __restrict__ counts,
           const float2* __restrict__ cand,
           float* __restrict__ out) {
  const int img = blockIdx.x;
  const int tid = threadIdx.x;
  const int n1 = min(counts[img], CAP);
  const int neff = min(n1, KTOP);
  const int Si = size_p[0];           // box side (4)
  const int A2 = 2 * Si * Si;         // iou > 0.1  <=>  11*inter > A2 (exact ints)
  const int R = Si - 1;               // max |dy|,|dx| for a conflict

  __shared__ int   px[KTOP];          // packed (y<<11)|x, slot order
  __shared__ float sc[KTOP];          // score, slot order
  __shared__ int   keep[KTOP];
  __shared__ int   spx[KTOP];         // packed pos, row-sorted order
  __shared__ int   sslot[KTOP];       // sorted pos -> slot
  __shared__ int   clslot[KTOP];      // conflicted slots (arbitrary order)
  __shared__ int   cls2[KTOP];        // conflicted slots, priority order
  __shared__ int   rc[1024];          // scan buffer
  __shared__ int   rowcnt[NH];        // histogram, then fill counters
  __shared__ int   ro[NH + 8];        // exclusive row offsets
  __shared__ int   ncl_sh, nfill_sh;
  __shared__ float bsc[CAP];          // slow-path originals
  __shared__ int   bpx[CAP];

  keep[tid] = 1;
  if (tid == 0) { ncl_sh = 0; nfill_sh = 0; }

  // ---- Phase A: load candidates into slot arrays (px, sc) ----
  if (n1 <= KTOP) {
    if (tid < n1) {
      const float2 e2 = cand[(size_t)img * CAP + tid];
      const int e = __float_as_int(e2.y);
      const int y = e / NW;
      px[tid] = (y << 11) | (e - y * NW);
      sc[tid] = e2.x;
    }
    __syncthreads();
  } else {
    // slow path: rank-filter to exactly the top-KTOP set (arbitrary order ok)
    for (int t = tid; t < n1; t += 1024) {
      const float2 e2 = cand[(size_t)img * CAP + t];
      const int e = __float_as_int(e2.y);
      const int y = e / NW;
      bpx[t] = (y << 11) | (e - y * NW);
      bsc[t] = e2.x;
    }
    __syncthreads();
    for (int t = tid; t < n1; t += 1024) {
      const float s = bsc[t];
      const int p = bpx[t];
      const int gidx = (p >> 11) * NW + (p & 2047);
      int r = 0;
      for (int i = 0; i < n1; ++i) {
        const float os = bsc[i];
        const int op = bpx[i];
        const int oidx = (op >> 11) * NW + (op & 2047);
        r += (os > s) || (os == s && oidx < gidx);
      }
      if (r < KTOP) {
        const int w = atomicAdd(&nfill_sh, 1);
        px[w] = p;
        sc[w] = s;
      }
    }
    __syncthreads();
  }

  // ---- Phase B: row histogram ----
  if (tid < NH) rowcnt[tid] = 0;
  __syncthreads();
  if (tid < neff) atomicAdd(&rowcnt[px[tid] >> 11], 1);
  __syncthreads();

  // ---- Phase C: inclusive scan -> exclusive row offsets ----
  rc[tid] = (tid < NH) ? rowcnt[tid] : 0;
  __syncthreads();
  if (tid < NH) rowcnt[tid] = 0;      // reuse as fill counters
  for (int off = 1; off < 1024; off <<= 1) {
    int v = rc[tid];
    if (tid >= off) v += rc[tid - off];
    __syncthreads();
    rc[tid] = v;
    __syncthreads();
  }
  if (tid == 0) ro[0] = 0;
  if (tid < NH) ro[tid + 1] = rc[tid];
  if (tid >= NH && tid < NH + 7) ro[tid + 1] = neff;
  __syncthreads();

  // ---- Phase D: scatter into row-sorted order ----
  if (tid < neff) {
    const int p = px[tid];
    const int y = p >> 11;
    const int pos = ro[y] + atomicAdd(&rowcnt[y], 1);
    spx[pos] = p;
    sslot[pos] = tid;
  }
  __syncthreads();

  // ---- Phase E: conflict scan over the 2R+1 row window (exact) ----
  if (tid < neff) {
    const int p = spx[tid];
    const int y = p >> 11, x = p & 2047;
    const int lo = ro[max(y - R, 0)];
    const int hi = ro[min(y + R, NH - 1) + 1];
    int conf = 0;
    for (int q = lo; q < hi; ++q) {
      if (q == tid) continue;
      const int op = spx[q];
      const int ady = abs(y - (op >> 11));
      const int adx = abs(x - (op & 2047));
      const int iy = Si - ady, ix = Si - adx;
      conf |= (iy > 0) & (ix > 0) & (11 * iy * ix > A2);
    }
    if (conf) {
      const int w = atomicAdd(&ncl_sh, 1);
      clslot[w] = sslot[tid];
    }
  }
  __syncthreads();
  const int k = ncl_sh;

  // ---- Phase F: sort conflicted subset by (score desc, idx asc) ----
  if (tid < k) {
    const int myslot = clslot[tid];
    const float ms = sc[myslot];
    const int mp = px[myslot];
    const int midx = (mp >> 11) * NW + (mp & 2047);
    int r = 0;
    for (int b = 0; b < k; ++b) {
      const int os_l = clslot[b];
      const float os = sc[os_l];
      const int op = px[os_l];
      const int oidx = (op >> 11) * NW + (op & 2047);
      r += (os > ms) || (os == ms && oidx < midx);
    }
    cls2[r] = myslot;
  }
  __syncthreads();

  // ---- Phase G: exact greedy over conflicted subset (wave 0) ----
  if (tid < 64) {
    for (int a = 1; a < k; ++a) {
      const int j = cls2[a];
      const int pj = px[j];
      const int yj = pj >> 11, xj = pj & 2047;
      bool sup = false;
      for (int base = 0; base < a; base += 64) {
        const int b = base + tid;
        bool hit = false;
        if (b < a) {
          const int i2 = cls2[b];
          if (keep[i2]) {
            const int op = px[i2];
            const int iy = Si - abs(yj - (op >> 11));
            const int ix = Si - abs(xj - (op & 2047));
            hit = (iy > 0) && (ix > 0) && (11 * iy * ix > A2);
          }
        }
        if (__any(hit)) { sup = true; break; }
      }
      if (tid == 0 && sup) keep[j] = 0;
    }
  }
  __syncthreads();

  // ---- Phase H: scatter kept scores ----
  if (tid < neff && keep[tid]) {
    const int p = px[tid];
    out[(size_t)img * NHW + (p >> 11) * NW + (p & 2047)] = sc[tid];
  }
}

// --------- fallback: monolithic per-image kernel (no workspace) ---------
__global__ __launch_bounds__(1024)
void k_nms_mono(const float* __restrict__ prob,
                const float* __restrict__ thr_p,
                const int* __restrict__ size_p,
                float* __restrict__ out) {
  const int img = blockIdx.x;
  const int tid = threadIdx.x;
  const float thr = thr_p[0];
  const float S = (float)size_p[0];
  const float A = 2.f * S * S;
  const float* ip = prob + (size_t)img * NHW;

  __shared__ float sc[CAP];
  __shared__ int   gi[CAP];
  __shared__ float ssc[KTOP];
  __shared__ int   sgi[KTOP];
  __shared__ int   keepf[KTOP];
  __shared__ int   sh_n;

  if (tid == 0) sh_n = 0;
  __syncthreads();
  for (int e = tid; e < NHW; e += 1024) {
    const float p = ip[e];
    if (p >= thr) {
      const int pos = atomicAdd(&sh_n, 1);
      if (pos < CAP) { sc[pos] = p; gi[pos] = e; }
    }
  }
  __syncthreads();
  const int n = min(sh_n, CAP);
  const int m = min(n, KTOP);

  for (int j = tid; j < n; j += 1024) {
    const float sj = sc[j]; const int gj = gi[j];
    int r = 0;
    for (int i = 0; i < n; ++i)
      r += (sc[i] > sj) || (sc[i] == sj && gi[i] < gj);
    if (r < KTOP) { ssc[r] = sj; sgi[r] = gj; }
  }
  keepf[tid] = (tid < m);
  __syncthreads();

  for (int i = 0; i < m; ++i) {
    __syncthreads();
    if (!keepf[i]) continue;
    const int g = sgi[i];
    const int yi0 = g / NW;
    const float yi = (float)yi0, xi = (float)(g - yi0 * NW);
    if (tid > i && tid < m && keepf[tid]) {
      const int g2 = sgi[tid];
      const int yj0 = g2 / NW;
      const float iy = S - fabsf(yi - (float)yj0);
      const float ix = S - fabsf(xi - (float)(g2 - yj0 * NW));
      if (fminf(iy, ix) > 0.f && 11.f * iy * ix > A) keepf[tid] = 0;
    }
  }
  __syncthreads();
  if (tid < m && keepf[tid])
    out[(size_t)img * NHW + sgi[tid]] = ssc[tid];
}

extern "C" void kernel_launch(void* const* d_in, const int* in_sizes, int n_in,
                              void* d_out, int out_size, void* d_ws, size_t ws_size,
                              hipStream_t stream) {
  const float* prob   = (const float*)d_in[0];
  const int*   size_p = (const int*)d_in[1];
  const float* thr_p  = (const float*)d_in[2];
  float* out = (float*)d_out;

  const size_t counts_b = 128;                              // NB ints, padded
  const size_t cand_b   = (size_t)NB * CAP * sizeof(float2);
  const size_t needed   = counts_b + cand_b;                // ~512 KB

  if (ws_size >= needed) {
    int*    counts = (int*)d_ws;
    float2* cand   = (float2*)((char*)d_ws + counts_b);
    (void)hipMemsetAsync(counts, 0, NB * sizeof(int), stream);
    k_zero_gather<<<NB * BPI, 256, 0, stream>>>(prob, thr_p, out, counts, cand);
    k_nms<<<NB, KTOP, 0, stream>>>(size_p, counts, cand, out);
  } else {
    k_zero_out<<<2048, 256, 0, stream>>>(out);
    k_nms_mono<<<NB, 1024, 0, stream>>>(prob, thr_p, size_p, out);
  }
}

// Round 6
// 53.456 us; speedup vs baseline: 3.1682x; 1.2626x over previous
//
#include <hip/hip_runtime.h>

#define NB 32
#define NH 720
#define NW 1280
#define NHW (NH * NW)        // 921600
#define NV4 (NHW / 4)        // 230400 float4 per image
#define KTOP 1024
#define CAP 2048             // per-image candidate cap (~830 expected)
#define BPI 60               // blocks per image
#define V4PB (NV4 / BPI)     // 3840 float4 per block (12 rows)
#define BATCH 5
#define OITER 3              // 15 float4 per thread = OITER * BATCH
#define LCAP 48              // per-block candidate slots (expected ~14, +9 sigma)

typedef float vf4 __attribute__((ext_vector_type(4)));   // native vector for nt-store

// ------- K1: zero the output map + gather candidates >= threshold -------
// Each block owns a contiguous 3840-float4 chunk fully inside one image.
// 5 loads in flight per wave; zero-fill via non-temporal stores. Candidates
// stage in LDS and flush to a FIXED per-block slot: no global atomics, no
// prior memset needed (cnt written unconditionally every call).
__global__ __launch_bounds__(256)
void k_zero_gather(const float* __restrict__ prob,
                   const float* __restrict__ thr_p,
                   float* __restrict__ out,
                   int* __restrict__ cnt,
                   float2* __restrict__ cand) {
  const int gblk = blockIdx.x;          // 0 .. NB*BPI-1
  const int img = gblk / BPI;
  const int blk = gblk - img * BPI;
  const float thr = thr_p[0];

  __shared__ int lcount;
  __shared__ float2 lcand[LCAP];
  if (threadIdx.x == 0) lcount = 0;
  __syncthreads();

  const float4* __restrict__ in4 =
      reinterpret_cast<const float4*>(prob) + (size_t)img * NV4 + blk * V4PB + threadIdx.x;
  vf4* __restrict__ out4 =
      reinterpret_cast<vf4*>(out) + (size_t)img * NV4 + blk * V4PB + threadIdx.x;
  const int idx0 = (blk * V4PB + threadIdx.x) * 4;   // flat idx within image
  const vf4 z = {0.f, 0.f, 0.f, 0.f};

#pragma unroll
  for (int it = 0; it < OITER; ++it) {
    const int o0 = (it * BATCH + 0) * 256;
    const int o1 = (it * BATCH + 1) * 256;
    const int o2 = (it * BATCH + 2) * 256;
    const int o3 = (it * BATCH + 3) * 256;
    const int o4 = (it * BATCH + 4) * 256;
    const float4 p0 = in4[o0];
    const float4 p1 = in4[o1];
    const float4 p2 = in4[o2];
    const float4 p3 = in4[o3];
    const float4 p4 = in4[o4];
    __builtin_nontemporal_store(z, &out4[o0]);
    __builtin_nontemporal_store(z, &out4[o1]);
    __builtin_nontemporal_store(z, &out4[o2]);
    __builtin_nontemporal_store(z, &out4[o3]);
    __builtin_nontemporal_store(z, &out4[o4]);
#define CHECKC(val, off, c)                                              \
    if ((val) >= thr) {                                                  \
      const int pos = atomicAdd(&lcount, 1);                             \
      if (pos < LCAP)                                                    \
        lcand[pos] = make_float2((val), __int_as_float(idx0 + (off) * 4 + (c))); \
    }
#define CHECK4(p, off) CHECKC((p).x, off, 0) CHECKC((p).y, off, 1) \
                       CHECKC((p).z, off, 2) CHECKC((p).w, off, 3)
    CHECK4(p0, o0) CHECK4(p1, o1) CHECK4(p2, o2) CHECK4(p3, o3) CHECK4(p4, o4)
#undef CHECK4
#undef CHECKC
  }
  __syncthreads();

  const int ln = min(lcount, LCAP);
  if (threadIdx.x == 0) cnt[gblk] = ln;
  for (int i = threadIdx.x; i < ln; i += 256)
    cand[(size_t)gblk * LCAP + i] = lcand[i];
}

// plain zeroing (fallback path)
__global__ void k_zero_out(float* __restrict__ out) {
  const int total4 = NB * NV4;
  const int stride = gridDim.x * blockDim.x;
  const float4 z = make_float4(0.f, 0.f, 0.f, 0.f);
  for (int v = blockIdx.x * blockDim.x + threadIdx.x; v < total4; v += stride)
    reinterpret_cast<float4*>(out)[v] = z;
}

// ---- K2: O(n * local) NMS via row-bucketed conflict detection ----
// One 1024-thread block per image. Compact the 60 per-block chunks (1 wave
// scan), counting-sort by row (2-level shfl scan, 3 barriers), 7-row-window
// conflict scan, sort the tiny conflicted subset by (score desc, idx asc),
// register-resident greedy on wave 0 (k<=64), scatter kept scores.
__global__ __launch_bounds__(1024)
void k_nms(const int* __restrict__ size_p,
           const int* __restrict__ cnt,
           const float2* __restrict__ cand,
           float* __restrict__ out) {
  const int img = blockIdx.x;
  const int tid = threadIdx.x;
  const int wid = tid >> 6, lane = tid & 63;
  const int Si = size_p[0];           // box side (4)
  const int A2 = 2 * Si * Si;         // iou > 0.1  <=>  11*inter > A2 (exact ints)
  const int R = Si - 1;               // max |dy|,|dx| for a conflict

  __shared__ int   px[KTOP];          // packed (y<<11)|x, slot order
  __shared__ float sc[KTOP];          // score, slot order
  __shared__ int   keep[KTOP];
  __shared__ int   spx[KTOP];         // packed pos, row-sorted order
  __shared__ int   sslot[KTOP];       // sorted pos -> slot
  __shared__ int   clslot[KTOP];      // conflicted slots (arbitrary order)
  __shared__ int   cls2[KTOP];        // conflicted slots, priority order
  __shared__ int   rowcnt[NH];        // histogram, then fill counters
  __shared__ int   ro[NH + 8];        // exclusive row offsets
  __shared__ int   coff[BPI + 1];     // chunk offsets
  __shared__ int   wsum[16];
  __shared__ int   ncl_sh, nfill_sh;
  __shared__ float bsc[CAP];          // slow-path staging
  __shared__ int   bpx[CAP];

  keep[tid] = 1;
  if (tid == 0) { ncl_sh = 0; nfill_sh = 0; }

  // ---- Phase A0: scan the 60 chunk counts (wave 0, no barrier inside) ----
  if (tid < 64) {
    int c = (tid < BPI) ? cnt[img * BPI + tid] : 0;
    int s = c;
#pragma unroll
    for (int d = 1; d < 64; d <<= 1) {
      const int u = __shfl_up(s, d, 64);
      if (lane >= d) s += u;
    }
    if (tid < BPI) coff[tid + 1] = s;
    if (tid == 0) coff[0] = 0;
  }
  __syncthreads();
  const int n1all = coff[BPI];
  const int n1 = min(n1all, CAP);
  const int neff = min(n1, KTOP);

  // ---- Phase A1: compact chunks into slot arrays ----
  if (n1all <= KTOP) {
    for (int t = tid; t < BPI * LCAP; t += 1024) {
      const int chunk = t / LCAP;
      const int i = t - chunk * LCAP;
      const int base = coff[chunk];
      if (i < coff[chunk + 1] - base) {
        const float2 e2 = cand[(size_t)(img * BPI + chunk) * LCAP + i];
        const int e = __float_as_int(e2.y);
        const int y = e / NW;
        px[base + i] = (y << 11) | (e - y * NW);
        sc[base + i] = e2.x;
      }
    }
    __syncthreads();
  } else {
    // slow path (never on this data): stage all, rank-filter to top-KTOP set
    for (int t = tid; t < BPI * LCAP; t += 1024) {
      const int chunk = t / LCAP;
      const int i = t - chunk * LCAP;
      const int base = coff[chunk];
      if (i < coff[chunk + 1] - base && base + i < CAP) {
        const float2 e2 = cand[(size_t)(img * BPI + chunk) * LCAP + i];
        const int e = __float_as_int(e2.y);
        const int y = e / NW;
        bpx[base + i] = (y << 11) | (e - y * NW);
        bsc[base + i] = e2.x;
      }
    }
    __syncthreads();
    for (int t = tid; t < n1; t += 1024) {
      const float s = bsc[t];
      const int p = bpx[t];
      const int gidx = (p >> 11) * NW + (p & 2047);
      int r = 0;
      for (int i = 0; i < n1; ++i) {
        const float os = bsc[i];
        const int op = bpx[i];
        const int oidx = (op >> 11) * NW + (op & 2047);
        r += (os > s) || (os == s && oidx < gidx);
      }
      if (r < KTOP) {
        const int w = atomicAdd(&nfill_sh, 1);
        px[w] = p;
        sc[w] = s;
      }
    }
    __syncthreads();
  }

  // ---- Phase B: row histogram ----
  if (tid < NH) rowcnt[tid] = 0;
  __syncthreads();
  if (tid < neff) atomicAdd(&rowcnt[px[tid] >> 11], 1);
  __syncthreads();

  // ---- Phase C: two-level shfl scan -> exclusive row offsets ----
  int v = (tid < NH) ? rowcnt[tid] : 0;
  if (tid < NH) rowcnt[tid] = 0;      // reuse as fill counters (own slot only)
#pragma unroll
  for (int d = 1; d < 64; d <<= 1) {
    const int u = __shfl_up(v, d, 64);
    if (lane >= d) v += u;
  }
  if (lane == 63 && wid < 12) wsum[wid] = v;
  __syncthreads();
  if (tid < 64) {
    int s = (tid < 12) ? wsum[tid] : 0;
#pragma unroll
    for (int d = 1; d < 16; d <<= 1) {
      const int u = __shfl_up(s, d, 64);
      if (lane >= d) s += u;
    }
    if (tid < 12) wsum[tid] = s;      // inclusive wave totals
  }
  __syncthreads();
  if (tid < NH) {
    const int base = (wid > 0) ? wsum[wid - 1] : 0;
    ro[tid + 1] = base + v;
  } else if (tid < NH + 7) {
    ro[tid + 1] = neff;
  }
  if (tid == 0) ro[0] = 0;
  __syncthreads();

  // ---- Phase D: scatter into row-sorted order ----
  if (tid < neff) {
    const int p = px[tid];
    const int y = p >> 11;
    const int pos = ro[y] + atomicAdd(&rowcnt[y], 1);
    spx[pos] = p;
    sslot[pos] = tid;
  }
  __syncthreads();

  // ---- Phase E: conflict scan over the 2R+1 row window (exact) ----
  if (tid < neff) {
    const int p = spx[tid];
    const int y = p >> 11, x = p & 2047;
    const int lo = ro[max(y - R, 0)];
    const int hi = ro[min(y + R, NH - 1) + 1];
    int conf = 0;
    for (int q = lo; q < hi; ++q) {
      if (q == tid) continue;
      const int op = spx[q];
      const int iy = Si - abs(y - (op >> 11));
      const int ix = Si - abs(x - (op & 2047));
      conf |= (iy > 0) & (ix > 0) & (11 * iy * ix > A2);
    }
    if (conf) {
      const int w = atomicAdd(&ncl_sh, 1);
      clslot[w] = sslot[tid];
    }
  }
  __syncthreads();
  const int k = ncl_sh;

  // ---- Phase F: sort conflicted subset by (score desc, idx asc) ----
  if (tid < k) {
    const int myslot = clslot[tid];
    const float ms = sc[myslot];
    const int mp = px[myslot];
    const int midx = (mp >> 11) * NW + (mp & 2047);
    int r = 0;
    for (int b = 0; b < k; ++b) {
      const int os_l = clslot[b];
      const float os = sc[os_l];
      const int op = px[os_l];
      const int oidx = (op >> 11) * NW + (op & 2047);
      r += (os > ms) || (os == ms && oidx < midx);
    }
    cls2[r] = myslot;
  }
  __syncthreads();

  // ---- Phase G: exact greedy over conflicted subset ----
  if (k <= 64) {
    // register-resident: lane a holds candidate a; broadcast via shfl.
    if (tid < 64) {
      const int slot = (tid < k) ? cls2[tid] : -1;
      const int p = (slot >= 0) ? px[slot] : 0;
      const int y = p >> 11, x = p & 2047;
      int keep_l = 1;
      for (int a = 1; a < k; ++a) {
        const int ya = __shfl(y, a, 64);
        const int xa = __shfl(x, a, 64);
        const int iy = Si - abs(ya - y);
        const int ix = Si - abs(xa - x);
        const bool hit = (tid < a) && keep_l && (iy > 0) && (ix > 0) &&
                         (11 * iy * ix > A2);
        const bool sup = __any(hit);
        if (tid == a && sup) keep_l = 0;
      }
      if (tid < k && !keep_l) keep[slot] = 0;
    }
  } else if (tid < 64) {
    // LDS fallback (k > 64; never on this data)
    for (int a = 1; a < k; ++a) {
      const int j = cls2[a];
      const int pj = px[j];
      const int yj = pj >> 11, xj = pj & 2047;
      bool sup = false;
      for (int base = 0; base < a; base += 64) {
        const int b = base + tid;
        bool hit = false;
        if (b < a) {
          const int i2 = cls2[b];
          if (keep[i2]) {
            const int op = px[i2];
            const int iy = Si - abs(yj - (op >> 11));
            const int ix = Si - abs(xj - (op & 2047));
            hit = (iy > 0) && (ix > 0) && (11 * iy * ix > A2);
          }
        }
        if (__any(hit)) { sup = true; break; }
      }
      if (tid == 0 && sup) keep[j] = 0;
    }
  }
  __syncthreads();

  // ---- Phase H: scatter kept scores ----
  if (tid < neff && keep[tid]) {
    const int p = px[tid];
    out[(size_t)img * NHW + (p >> 11) * NW + (p & 2047)] = sc[tid];
  }
}

// --------- fallback: monolithic per-image kernel (no workspace) ---------
__global__ __launch_bounds__(1024)
void k_nms_mono(const float* __restrict__ prob,
                const float* __restrict__ thr_p,
                const int* __restrict__ size_p,
                float* __restrict__ out) {
  const int img = blockIdx.x;
  const int tid = threadIdx.x;
  const float thr = thr_p[0];
  const float S = (float)size_p[0];
  const float A = 2.f * S * S;
  const float* ip = prob + (size_t)img * NHW;

  __shared__ float sc[CAP];
  __shared__ int   gi[CAP];
  __shared__ float ssc[KTOP];
  __shared__ int   sgi[KTOP];
  __shared__ int   keepf[KTOP];
  __shared__ int   sh_n;

  if (tid == 0) sh_n = 0;
  __syncthreads();
  for (int e = tid; e < NHW; e += 1024) {
    const float p = ip[e];
    if (p >= thr) {
      const int pos = atomicAdd(&sh_n, 1);
      if (pos < CAP) { sc[pos] = p; gi[pos] = e; }
    }
  }
  __syncthreads();
  const int n = min(sh_n, CAP);
  const int m = min(n, KTOP);

  for (int j = tid; j < n; j += 1024) {
    const float sj = sc[j]; const int gj = gi[j];
    int r = 0;
    for (int i = 0; i < n; ++i)
      r += (sc[i] > sj) || (sc[i] == sj && gi[i] < gj);
    if (r < KTOP) { ssc[r] = sj; sgi[r] = gj; }
  }
  keepf[tid] = (tid < m);
  __syncthreads();

  for (int i = 0; i < m; ++i) {
    __syncthreads();
    if (!keepf[i]) continue;
    const int g = sgi[i];
    const int yi0 = g / NW;
    const float yi = (float)yi0, xi = (float)(g - yi0 * NW);
    if (tid > i && tid < m && keepf[tid]) {
      const int g2 = sgi[tid];
      const int yj0 = g2 / NW;
      const float iy = S - fabsf(yi - (float)yj0);
      const float ix = S - fabsf(xi - (float)(g2 - yj0 * NW));
      if (fminf(iy, ix) > 0.f && 11.f * iy * ix > A) keepf[tid] = 0;
    }
  }
  __syncthreads();
  if (tid < m && keepf[tid])
    out[(size_t)img * NHW + sgi[tid]] = ssc[tid];
}

extern "C" void kernel_launch(void* const* d_in, const int* in_sizes, int n_in,
                              void* d_out, int out_size, void* d_ws, size_t ws_size,
                              hipStream_t stream) {
  const float* prob   = (const float*)d_in[0];
  const int*   size_p = (const int*)d_in[1];
  const float* thr_p  = (const float*)d_in[2];
  float* out = (float*)d_out;

  const size_t cnt_b  = (size_t)NB * BPI * sizeof(int);            // 7.7 KB
  const size_t cand_b = (size_t)NB * BPI * LCAP * sizeof(float2);  // 737 KB
  const size_t needed = cnt_b + cand_b;                            // ~745 KB

  if (ws_size >= needed) {
    int*    cnt  = (int*)d_ws;
    float2* cand = (float2*)((char*)d_ws + cnt_b);
    k_zero_gather<<<NB * BPI, 256, 0, stream>>>(prob, thr_p, out, cnt, cand);
    k_nms<<<NB, KTOP, 0, stream>>>(size_p, cnt, cand, out);
  } else {
    k_zero_out<<<2048, 256, 0, stream>>>(out);
    k_nms_mono<<<NB, 1024, 0, stream>>>(prob, thr_p, size_p, out);
  }
}

// Round 7
// 51.895 us; speedup vs baseline: 3.2635x; 1.0301x over previous
//
#include <hip/hip_runtime.h>

#define NB 32
#define NH 720
#define NW 1280
#define NHW (NH * NW)        // 921600
#define NV4 (NHW / 4)        // 230400 float4 per image
#define KTOP 1024
#define CAP 2048             // per-image candidate cap (~830 expected)
#define BPI 60               // gather blocks per image
#define V4PB (NV4 / BPI)     // 3840 float4 per block (12 rows)
#define BATCH 5
#define OITER 3              // 15 float4 per thread = OITER * BATCH
#define LCAP 48              // per-block candidate slots (expected ~14, +9 sigma)
#define NGB (NB * BPI)       // 1920 gather blocks
#define NZB 1920             // zero blocks (NB*NV4 / V4PB)

typedef float vf4 __attribute__((ext_vector_type(4)));   // native vector for nt-store

// ---- K1: block-role-split zero + gather (one dispatch, decoupled streams) ----
// Even blocks: LOAD-ONLY gather over a contiguous 3840-float4 chunk of prob
//   (no stores in the wave's vmcnt stream -> load-use waits never drain stores).
// Odd blocks: STORE-ONLY nt zero-fill of the output map (never waits on vmcnt).
// Read and write streams mix at the memory controllers chip-wide.
__global__ __launch_bounds__(256)
void k_zero_gather(const float* __restrict__ prob,
                   const float* __restrict__ thr_p,
                   float* __restrict__ out,
                   int* __restrict__ cnt,
                   float2* __restrict__ cand) {
  const int b = blockIdx.x;

  if (b & 1) {
    // -------- zero role --------
    const int zb = b >> 1;
    vf4* __restrict__ out4 =
        reinterpret_cast<vf4*>(out) + (size_t)zb * V4PB + threadIdx.x;
    const vf4 z = {0.f, 0.f, 0.f, 0.f};
#pragma unroll
    for (int it = 0; it < OITER * BATCH; ++it)
      __builtin_nontemporal_store(z, &out4[it * 256]);
    return;
  }

  // -------- gather role --------
  const int gblk = b >> 1;              // 0 .. NGB-1
  const int img = gblk / BPI;
  const int blk = gblk - img * BPI;
  const float thr = thr_p[0];

  __shared__ int lcount;
  __shared__ float2 lcand[LCAP];
  if (threadIdx.x == 0) lcount = 0;
  __syncthreads();

  const float4* __restrict__ in4 =
      reinterpret_cast<const float4*>(prob) + (size_t)img * NV4 + blk * V4PB + threadIdx.x;
  const int idx0 = (blk * V4PB + threadIdx.x) * 4;   // flat idx within image

#pragma unroll
  for (int it = 0; it < OITER; ++it) {
    const int o0 = (it * BATCH + 0) * 256;
    const int o1 = (it * BATCH + 1) * 256;
    const int o2 = (it * BATCH + 2) * 256;
    const int o3 = (it * BATCH + 3) * 256;
    const int o4 = (it * BATCH + 4) * 256;
    const float4 p0 = in4[o0];
    const float4 p1 = in4[o1];
    const float4 p2 = in4[o2];
    const float4 p3 = in4[o3];
    const float4 p4 = in4[o4];
#define CHECKC(val, off, c)                                              \
    if ((val) >= thr) {                                                  \
      const int pos = atomicAdd(&lcount, 1);                             \
      if (pos < LCAP)                                                    \
        lcand[pos] = make_float2((val), __int_as_float(idx0 + (off) * 4 + (c))); \
    }
#define CHECK4(p, off) CHECKC((p).x, off, 0) CHECKC((p).y, off, 1) \
                       CHECKC((p).z, off, 2) CHECKC((p).w, off, 3)
    CHECK4(p0, o0) CHECK4(p1, o1) CHECK4(p2, o2) CHECK4(p3, o3) CHECK4(p4, o4)
#undef CHECK4
#undef CHECKC
  }
  __syncthreads();

  const int ln = min(lcount, LCAP);
  if (threadIdx.x == 0) cnt[gblk] = ln;
  for (int i = threadIdx.x; i < ln; i += 256)
    cand[(size_t)gblk * LCAP + i] = lcand[i];
}

// plain zeroing (fallback path)
__global__ void k_zero_out(float* __restrict__ out) {
  const int total4 = NB * NV4;
  const int stride = gridDim.x * blockDim.x;
  const float4 z = make_float4(0.f, 0.f, 0.f, 0.f);
  for (int v = blockIdx.x * blockDim.x + threadIdx.x; v < total4; v += stride)
    reinterpret_cast<float4*>(out)[v] = z;
}

// ---- K2: O(n * local) NMS via row-bucketed conflict detection ----
// One 1024-thread block per image. Compact the 60 per-block chunks (1 wave
// scan), counting-sort by row (2-level shfl scan, 3 barriers), 7-row-window
// conflict scan, sort the tiny conflicted subset by (score desc, idx asc),
// register-resident greedy on wave 0 (k<=64), scatter kept scores.
__global__ __launch_bounds__(1024)
void k_nms(const int* __restrict__ size_p,
           const int* __restrict__ cnt,
           const float2* __restrict__ cand,
           float* __restrict__ out) {
  const int img = blockIdx.x;
  const int tid = threadIdx.x;
  const int wid = tid >> 6, lane = tid & 63;
  const int Si = size_p[0];           // box side (4)
  const int A2 = 2 * Si * Si;         // iou > 0.1  <=>  11*inter > A2 (exact ints)
  const int R = Si - 1;               // max |dy|,|dx| for a conflict

  __shared__ int   px[KTOP];          // packed (y<<11)|x, slot order
  __shared__ float sc[KTOP];          // score, slot order
  __shared__ int   keep[KTOP];
  __shared__ int   spx[KTOP];         // packed pos, row-sorted order
  __shared__ int   sslot[KTOP];       // sorted pos -> slot
  __shared__ int   clslot[KTOP];      // conflicted slots (arbitrary order)
  __shared__ int   cls2[KTOP];        // conflicted slots, priority order
  __shared__ int   rowcnt[NH];        // histogram, then fill counters
  __shared__ int   ro[NH + 8];        // exclusive row offsets
  __shared__ int   coff[BPI + 1];     // chunk offsets
  __shared__ int   wsum[16];
  __shared__ int   ncl_sh, nfill_sh;
  __shared__ float bsc[CAP];          // slow-path staging
  __shared__ int   bpx[CAP];

  keep[tid] = 1;
  if (tid == 0) { ncl_sh = 0; nfill_sh = 0; }

  // ---- Phase A0: scan the 60 chunk counts (wave 0, no barrier inside) ----
  if (tid < 64) {
    int c = (tid < BPI) ? cnt[img * BPI + tid] : 0;
    int s = c;
#pragma unroll
    for (int d = 1; d < 64; d <<= 1) {
      const int u = __shfl_up(s, d, 64);
      if (lane >= d) s += u;
    }
    if (tid < BPI) coff[tid + 1] = s;
    if (tid == 0) coff[0] = 0;
  }
  __syncthreads();
  const int n1all = coff[BPI];
  const int n1 = min(n1all, CAP);
  const int neff = min(n1, KTOP);

  // ---- Phase A1: compact chunks into slot arrays ----
  if (n1all <= KTOP) {
    for (int t = tid; t < BPI * LCAP; t += 1024) {
      const int chunk = t / LCAP;
      const int i = t - chunk * LCAP;
      const int base = coff[chunk];
      if (i < coff[chunk + 1] - base) {
        const float2 e2 = cand[(size_t)(img * BPI + chunk) * LCAP + i];
        const int e = __float_as_int(e2.y);
        const int y = e / NW;
        px[base + i] = (y << 11) | (e - y * NW);
        sc[base + i] = e2.x;
      }
    }
    __syncthreads();
  } else {
    // slow path (never on this data): stage all, rank-filter to top-KTOP set
    for (int t = tid; t < BPI * LCAP; t += 1024) {
      const int chunk = t / LCAP;
      const int i = t - chunk * LCAP;
      const int base = coff[chunk];
      if (i < coff[chunk + 1] - base && base + i < CAP) {
        const float2 e2 = cand[(size_t)(img * BPI + chunk) * LCAP + i];
        const int e = __float_as_int(e2.y);
        const int y = e / NW;
        bpx[base + i] = (y << 11) | (e - y * NW);
        bsc[base + i] = e2.x;
      }
    }
    __syncthreads();
    for (int t = tid; t < n1; t += 1024) {
      const float s = bsc[t];
      const int p = bpx[t];
      const int gidx = (p >> 11) * NW + (p & 2047);
      int r = 0;
      for (int i = 0; i < n1; ++i) {
        const float os = bsc[i];
        const int op = bpx[i];
        const int oidx = (op >> 11) * NW + (op & 2047);
        r += (os > s) || (os == s && oidx < gidx);
      }
      if (r < KTOP) {
        const int w = atomicAdd(&nfill_sh, 1);
        px[w] = p;
        sc[w] = s;
      }
    }
    __syncthreads();
  }

  // ---- Phase B: row histogram ----
  if (tid < NH) rowcnt[tid] = 0;
  __syncthreads();
  if (tid < neff) atomicAdd(&rowcnt[px[tid] >> 11], 1);
  __syncthreads();

  // ---- Phase C: two-level shfl scan -> exclusive row offsets ----
  int v = (tid < NH) ? rowcnt[tid] : 0;
  if (tid < NH) rowcnt[tid] = 0;      // reuse as fill counters (own slot only)
#pragma unroll
  for (int d = 1; d < 64; d <<= 1) {
    const int u = __shfl_up(v, d, 64);
    if (lane >= d) v += u;
  }
  if (lane == 63 && wid < 12) wsum[wid] = v;
  __syncthreads();
  if (tid < 64) {
    int s = (tid < 12) ? wsum[tid] : 0;
#pragma unroll
    for (int d = 1; d < 16; d <<= 1) {
      const int u = __shfl_up(s, d, 64);
      if (lane >= d) s += u;
    }
    if (tid < 12) wsum[tid] = s;      // inclusive wave totals
  }
  __syncthreads();
  if (tid < NH) {
    const int base = (wid > 0) ? wsum[wid - 1] : 0;
    ro[tid + 1] = base + v;
  } else if (tid < NH + 7) {
    ro[tid + 1] = neff;
  }
  if (tid == 0) ro[0] = 0;
  __syncthreads();

  // ---- Phase D: scatter into row-sorted order ----
  if (tid < neff) {
    const int p = px[tid];
    const int y = p >> 11;
    const int pos = ro[y] + atomicAdd(&rowcnt[y], 1);
    spx[pos] = p;
    sslot[pos] = tid;
  }
  __syncthreads();

  // ---- Phase E: conflict scan over the 2R+1 row window (exact) ----
  if (tid < neff) {
    const int p = spx[tid];
    const int y = p >> 11, x = p & 2047;
    const int lo = ro[max(y - R, 0)];
    const int hi = ro[min(y + R, NH - 1) + 1];
    int conf = 0;
    for (int q = lo; q < hi; ++q) {
      if (q == tid) continue;
      const int op = spx[q];
      const int iy = Si - abs(y - (op >> 11));
      const int ix = Si - abs(x - (op & 2047));
      conf |= (iy > 0) & (ix > 0) & (11 * iy * ix > A2);
    }
    if (conf) {
      const int w = atomicAdd(&ncl_sh, 1);
      clslot[w] = sslot[tid];
    }
  }
  __syncthreads();
  const int k = ncl_sh;

  // ---- Phase F: sort conflicted subset by (score desc, idx asc) ----
  if (tid < k) {
    const int myslot = clslot[tid];
    const float ms = sc[myslot];
    const int mp = px[myslot];
    const int midx = (mp >> 11) * NW + (mp & 2047);
    int r = 0;
    for (int b2 = 0; b2 < k; ++b2) {
      const int os_l = clslot[b2];
      const float os = sc[os_l];
      const int op = px[os_l];
      const int oidx = (op >> 11) * NW + (op & 2047);
      r += (os > ms) || (os == ms && oidx < midx);
    }
    cls2[r] = myslot;
  }
  __syncthreads();

  // ---- Phase G: exact greedy over conflicted subset ----
  if (k <= 64) {
    // register-resident: lane a holds candidate a; broadcast via shfl.
    if (tid < 64) {
      const int slot = (tid < k) ? cls2[tid] : -1;
      const int p = (slot >= 0) ? px[slot] : 0;
      const int y = p >> 11, x = p & 2047;
      int keep_l = 1;
      for (int a = 1; a < k; ++a) {
        const int ya = __shfl(y, a, 64);
        const int xa = __shfl(x, a, 64);
        const int iy = Si - abs(ya - y);
        const int ix = Si - abs(xa - x);
        const bool hit = (tid < a) && keep_l && (iy > 0) && (ix > 0) &&
                         (11 * iy * ix > A2);
        const bool sup = __any(hit);
        if (tid == a && sup) keep_l = 0;
      }
      if (tid < k && !keep_l) keep[slot] = 0;
    }
  } else if (tid < 64) {
    // LDS fallback (k > 64; never on this data)
    for (int a = 1; a < k; ++a) {
      const int j = cls2[a];
      const int pj = px[j];
      const int yj = pj >> 11, xj = pj & 2047;
      bool sup = false;
      for (int base = 0; base < a; base += 64) {
        const int b2 = base + tid;
        bool hit = false;
        if (b2 < a) {
          const int i2 = cls2[b2];
          if (keep[i2]) {
            const int op = px[i2];
            const int iy = Si - abs(yj - (op >> 11));
            const int ix = Si - abs(xj - (op & 2047));
            hit = (iy > 0) && (ix > 0) && (11 * iy * ix > A2);
          }
        }
        if (__any(hit)) { sup = true; break; }
      }
      if (tid == 0 && sup) keep[j] = 0;
    }
  }
  __syncthreads();

  // ---- Phase H: scatter kept scores ----
  if (tid < neff && keep[tid]) {
    const int p = px[tid];
    out[(size_t)img * NHW + (p >> 11) * NW + (p & 2047)] = sc[tid];
  }
}

// --------- fallback: monolithic per-image kernel (no workspace) ---------
__global__ __launch_bounds__(1024)
void k_nms_mono(const float* __restrict__ prob,
                const float* __restrict__ thr_p,
                const int* __restrict__ size_p,
                float* __restrict__ out) {
  const int img = blockIdx.x;
  const int tid = threadIdx.x;
  const float thr = thr_p[0];
  const float S = (float)size_p[0];
  const float A = 2.f * S * S;
  const float* ip = prob + (size_t)img * NHW;

  __shared__ float sc[CAP];
  __shared__ int   gi[CAP];
  __shared__ float ssc[KTOP];
  __shared__ int   sgi[KTOP];
  __shared__ int   keepf[KTOP];
  __shared__ int   sh_n;

  if (tid == 0) sh_n = 0;
  __syncthreads();
  for (int e = tid; e < NHW; e += 1024) {
    const float p = ip[e];
    if (p >= thr) {
      const int pos = atomicAdd(&sh_n, 1);
      if (pos < CAP) { sc[pos] = p; gi[pos] = e; }
    }
  }
  __syncthreads();
  const int n = min(sh_n, CAP);
  const int m = min(n, KTOP);

  for (int j = tid; j < n; j += 1024) {
    const float sj = sc[j]; const int gj = gi[j];
    int r = 0;
    for (int i = 0; i < n; ++i)
      r += (sc[i] > sj) || (sc[i] == sj && gi[i] < gj);
    if (r < KTOP) { ssc[r] = sj; sgi[r] = gj; }
  }
  keepf[tid] = (tid < m);
  __syncthreads();

  for (int i = 0; i < m; ++i) {
    __syncthreads();
    if (!keepf[i]) continue;
    const int g = sgi[i];
    const int yi0 = g / NW;
    const float yi = (float)yi0, xi = (float)(g - yi0 * NW);
    if (tid > i && tid < m && keepf[tid]) {
      const int g2 = sgi[tid];
      const int yj0 = g2 / NW;
      const float iy = S - fabsf(yi - (float)yj0);
      const float ix = S - fabsf(xi - (float)(g2 - yj0 * NW));
      if (fminf(iy, ix) > 0.f && 11.f * iy * ix > A) keepf[tid] = 0;
    }
  }
  __syncthreads();
  if (tid < m && keepf[tid])
    out[(size_t)img * NHW + sgi[tid]] = ssc[tid];
}

extern "C" void kernel_launch(void* const* d_in, const int* in_sizes, int n_in,
                              void* d_out, int out_size, void* d_ws, size_t ws_size,
                              hipStream_t stream) {
  const float* prob   = (const float*)d_in[0];
  const int*   size_p = (const int*)d_in[1];
  const float* thr_p  = (const float*)d_in[2];
  float* out = (float*)d_out;

  const size_t cnt_b  = (size_t)NGB * sizeof(int);            // 7.7 KB
  const size_t cand_b = (size_t)NGB * LCAP * sizeof(float2);  // 737 KB
  const size_t needed = cnt_b + cand_b;                       // ~745 KB

  if (ws_size >= needed) {
    int*    cnt  = (int*)d_ws;
    float2* cand = (float2*)((char*)d_ws + cnt_b);
    k_zero_gather<<<NGB + NZB, 256, 0, stream>>>(prob, thr_p, out, cnt, cand);
    k_nms<<<NB, KTOP, 0, stream>>>(size_p, cnt, cand, out);
  } else {
    k_zero_out<<<2048, 256, 0, stream>>>(out);
    k_nms_mono<<<NB, 1024, 0, stream>>>(prob, thr_p, size_p, out);
  }
}